// Round 2
// baseline (653.578 us; speedup 1.0000x reference)
//
#include <hip/hip_runtime.h>
#include <math.h>

// feat_1: (16,32,256,256) f32; feat_2: (16,32,64,64) f32; xcorr/out: (16,32,319,319) f32
#define H1 256
#define W1 256
#define HO 319
#define WO 319
#define SEG 16           // row segments per channel; one WAVE per (channel, segment)
#define ROWS_PER 20      // ceil(319/16)

__device__ __forceinline__ float up0(float x, int d, int lane) {
  float s = __shfl_up(x, (unsigned)d, 64);
  return (lane >= d) ? s : 0.0f;
}
__device__ __forceinline__ float dn0(float x, int d, int lane) {
  float s = __shfl_down(x, (unsigned)d, 64);
  return (lane + d <= 63) ? s : 0.0f;
}

// Given this lane's 4 column values a0..a3 (cols 4*lane .. 4*lane+3, all >= 0),
// produce the 64-wide windowed sums:
//   wi[j]: window ending at xo = 4*lane+j        (interior, clipped at 0)
//   wt[j]: window ending at xo = 256+4*lane+j    (tail, clipped at 255)
// All values are built from ADDITIONS of in-window values only -> no cancellation.
__device__ __forceinline__ void win7(float a0, float a1, float a2, float a3,
                                     int lane, float wi[4], float wt[4]) {
  float L0 = a0, L1 = L0 + a1, L2 = L1 + a2, L3 = L2 + a3;  // in-thread prefixes
  float sf2 = a3, sf1 = sf2 + a2, sf0 = sf1 + a1;           // in-thread suffixes (slots > j)
  // backward windowed sums of thread totals (pow2 doubling)
  float b1 = L3 + up0(L3, 1, lane);   // 2-window incl
  float b2 = b1 + up0(b1, 2, lane);   // 4-window incl
  float b3 = b2 + up0(b2, 4, lane);   // 8-window incl
  // M = sum of totals over lanes [lane-15, lane-1] (clipped at 0): 8+4+2+1 decomposition
  float M = up0(b3, 1, lane) + up0(b2, 9, lane) + up0(b1, 13, lane) + up0(L3, 15, lane);
  // forward 16-window inclusive of totals (for right-clipped tail windows)
  float c1 = L3 + dn0(L3, 1, lane);
  float c2 = c1 + dn0(c1, 2, lane);
  float c3 = c2 + dn0(c2, 4, lane);
  float c4 = c3 + dn0(c3, 8, lane);
  float T49 = dn0(c4, 49, lane);      // sum of totals over lanes [lane+49, 63]
  // partial-thread pieces from lane-16 (interior) and lane+48 (tail)
  float g0 = up0(sf0, 16, lane), g1 = up0(sf1, 16, lane), g2 = up0(sf2, 16, lane);
  float h0 = dn0(sf0, 48, lane), h1 = dn0(sf1, 48, lane), h2 = dn0(sf2, 48, lane);
  wi[0] = g0 + M + L0;  wi[1] = g1 + M + L1;  wi[2] = g2 + M + L2;  wi[3] = M + L3;
  wt[0] = h0 + T49;     wt[1] = h1 + T49;     wt[2] = h2 + T49;     wt[3] = T49;
}

__device__ __forceinline__ float out_val(float ws, float ws2, float xc,
                                         float mean, float ssd) {
  const float FLOOR_  = 1.1920928955078125e-07f;  // float32 eps
  const float FLOOR2_ = FLOOR_ * FLOOR_;
  float num  = xc - ws * mean;
  float w2c  = ws2 - ws * ws * (1.0f / 4096.0f);
  float t    = fmaxf(w2c * ssd, 0.0f);            // denom^2
  float numc = fmaxf(num, FLOOR_);                // (num << FLT_MAX always; skip upper clip)
  return (t > FLOOR2_) ? (numc * __frsqrt_rn(t)) : 0.0f;
}

__global__ __launch_bounds__(256, 8)
void ncc_norm_kernel(const float* __restrict__ feat1,
                     const float* __restrict__ feat2,
                     const float* __restrict__ xcorr,
                     float* __restrict__ out) {
  const int tid  = threadIdx.x;
  const int lane = tid & 63;
  const int wv   = tid >> 6;

  // XCD-chunked swizzle (grid = 2048 = 8 XCD * 256, bijective):
  // block d lands on XCD d&7; give that XCD a contiguous chunk of 64 channels,
  // with a channel's 4 blocks adjacent in dispatch order on the same XCD.
  const int d   = blockIdx.x;          // 0..2047
  const int xcd = d & 7;
  const int i   = d >> 3;              // 0..255
  const int bc  = xcd * 64 + (i >> 2); // 0..511 channel
  const int seg = (i & 3) * 4 + wv;    // 0..15 row segment

  const float* f1 = feat1 + (size_t)bc * (H1 * W1);
  const float* f2 = feat2 + (size_t)bc * 4096;

  // ---- per-wave feat_2 stats (no cross-wave sync needed) ----
  float sum = 0.0f, sumsq = 0.0f;
  #pragma unroll
  for (int r = 0; r < 16; ++r) {
    float4 q = *(const float4*)(f2 + r * 256 + 4 * lane);
    sum   += (q.x + q.y) + (q.z + q.w);
    sumsq += (q.x * q.x + q.y * q.y) + (q.z * q.z + q.w * q.w);
  }
  #pragma unroll
  for (int dd = 1; dd < 64; dd <<= 1) {
    sum   += __shfl_xor(sum,   dd, 64);
    sumsq += __shfl_xor(sumsq, dd, 64);
  }
  float mean = sum * (1.0f / 4096.0f);
  float ssd  = sumsq - sum * mean;   // sum((x-mean)^2); terms ~4096 vs ~1, no cancellation

  const int y0 = seg * ROWS_PER;
  const int y1 = min(HO, y0 + ROWS_PER);
  const int x4 = 4 * lane;

  // ---- vertical running window sums (fp64 registers; exact to ~1e-12) ----
  double v0 = 0, v1 = 0, v2 = 0, v3 = 0;      // sum of f1 over vertical window, per slot
  double q0 = 0, q1 = 0, q2 = 0, q3 = 0;      // sum of f1^2
  for (int r = max(0, y0 - 64); r < min(y0, H1); ++r) {
    float4 t = *(const float4*)(f1 + r * W1 + x4);
    v0 += t.x; q0 += (double)t.x * t.x;
    v1 += t.y; q1 += (double)t.y * t.y;
    v2 += t.z; q2 += (double)t.z * t.z;
    v3 += t.w; q3 += (double)t.w * t.w;
  }

  // ---- software prefetch of entering/leaving feat_1 rows ----
  float4 tE, tL;
  if (y0 < H1)  tE = *(const float4*)(f1 + y0 * W1 + x4);
  if (y0 >= 64) tL = *(const float4*)(f1 + (y0 - 64) * W1 + x4);

  for (int y = y0; y < y1; ++y) {
    const int rowbase = (bc * HO + y) * WO;
    const float* xr  = xcorr + rowbase;
    float*       orw = out   + rowbase;

    // issue this row's streaming xcorr loads first
    float xi[4];
    #pragma unroll
    for (int j = 0; j < 4; ++j) xi[j] = xr[x4 + j];
    float xt[4] = {0.0f, 0.0f, 0.0f, 0.0f};
    if (lane < 16) {
      xt[0] = xr[256 + x4 + 0];
      xt[1] = xr[256 + x4 + 1];
      xt[2] = xr[256 + x4 + 2];
      if (lane < 15) xt[3] = xr[256 + x4 + 3];
    }

    // consume prefetched rows (uniform branches)
    if (y < H1) {
      v0 += tE.x; q0 += (double)tE.x * tE.x;
      v1 += tE.y; q1 += (double)tE.y * tE.y;
      v2 += tE.z; q2 += (double)tE.z * tE.z;
      v3 += tE.w; q3 += (double)tE.w * tE.w;
    }
    if (y >= 64) {
      v0 -= tL.x; q0 -= (double)tL.x * tL.x;
      v1 -= tL.y; q1 -= (double)tL.y * tL.y;
      v2 -= tL.z; q2 -= (double)tL.z * tL.z;
      v3 -= tL.w; q3 -= (double)tL.w * tL.w;
    }

    // prefetch rows for iteration y+1 (hide L2/HBM latency under win7 chain)
    {
      int yn = y + 1;
      if (yn < y1) {
        if (yn < H1)  tE = *(const float4*)(f1 + yn * W1 + x4);
        if (yn >= 64) tL = *(const float4*)(f1 + (yn - 64) * W1 + x4);
      }
    }

    // fp32 per-column vertical sums for this output row
    float w0 = (float)v0, w1 = (float)v1, w2 = (float)v2, w3 = (float)v3;
    float u0 = (float)q0, u1 = (float)q1, u2 = (float)q2, u3 = (float)q3;

    float wsI[4], wsT[4], sqI[4], sqT[4];
    win7(w0, w1, w2, w3, lane, wsI, wsT);
    win7(u0, u1, u2, u3, lane, sqI, sqT);

    // interior outputs xo = 4*lane + j (rows are 319 floats -> 4B aligned: scalar I/O)
    #pragma unroll
    for (int j = 0; j < 4; ++j)
      orw[x4 + j] = out_val(wsI[j], sqI[j], xi[j], mean, ssd);
    // tail outputs xo = 256 + 4*lane + j (lanes 0..15 only; 63 elements)
    if (lane < 16) {
      orw[256 + x4 + 0] = out_val(wsT[0], sqT[0], xt[0], mean, ssd);
      orw[256 + x4 + 1] = out_val(wsT[1], sqT[1], xt[1], mean, ssd);
      orw[256 + x4 + 2] = out_val(wsT[2], sqT[2], xt[2], mean, ssd);
      if (lane < 15)
        orw[256 + x4 + 3] = out_val(wsT[3], sqT[3], xt[3], mean, ssd);
    }
  }
}

extern "C" void kernel_launch(void* const* d_in, const int* in_sizes, int n_in,
                              void* d_out, int out_size, void* d_ws, size_t ws_size,
                              hipStream_t stream) {
  const float* feat1 = (const float*)d_in[0];
  const float* feat2 = (const float*)d_in[1];
  const float* xcorr = (const float*)d_in[2];
  float* out = (float*)d_out;

  dim3 grid(512 * SEG / 4);   // 2048 blocks, 4 waves/block, one wave per (channel, segment)
  ncc_norm_kernel<<<grid, 256, 0, stream>>>(feat1, feat2, xcorr, out);
}

// Round 3
// 488.557 us; speedup vs baseline: 1.3378x; 1.3378x over previous
//
#include <hip/hip_runtime.h>
#include <math.h>

// feat_1: (16,32,256,256) f32; feat_2: (16,32,64,64) f32; xcorr/out: (16,32,319,319) f32
#define H1 256
#define W1 256
#define HO 319
#define WO 319
#define SEG 8            // row segments per channel; one WAVE per (channel, segment)
#define ROWS_PER 40      // 319/8 rounded up

__device__ __forceinline__ float up0(float x, int d, int lane) {
  float s = __shfl_up(x, (unsigned)d, 64);
  return (lane >= d) ? s : 0.0f;
}
__device__ __forceinline__ float dn0(float x, int d, int lane) {
  float s = __shfl_down(x, (unsigned)d, 64);
  return (lane + d <= 63) ? s : 0.0f;
}

// Given this lane's 4 column values a0..a3 (cols 4*lane .. 4*lane+3, all >= 0),
// produce the 64-wide windowed sums:
//   wi[j]: window ending at xo = 4*lane+j        (interior, clipped at 0)
//   wt[j]: window ending at xo = 256+4*lane+j    (tail, clipped at 255)
__device__ __forceinline__ void win7(float a0, float a1, float a2, float a3,
                                     int lane, float wi[4], float wt[4]) {
  float L0 = a0, L1 = L0 + a1, L2 = L1 + a2, L3 = L2 + a3;  // in-thread prefixes
  float sf2 = a3, sf1 = sf2 + a2, sf0 = sf1 + a1;           // in-thread suffixes (slots > j)
  float b1 = L3 + up0(L3, 1, lane);   // 2-window incl
  float b2 = b1 + up0(b1, 2, lane);   // 4-window incl
  float b3 = b2 + up0(b2, 4, lane);   // 8-window incl
  float M = up0(b3, 1, lane) + up0(b2, 9, lane) + up0(b1, 13, lane) + up0(L3, 15, lane);
  float c1 = L3 + dn0(L3, 1, lane);
  float c2 = c1 + dn0(c1, 2, lane);
  float c3 = c2 + dn0(c2, 4, lane);
  float c4 = c3 + dn0(c3, 8, lane);
  float T49 = dn0(c4, 49, lane);      // sum of totals over lanes [lane+49, 63]
  float g0 = up0(sf0, 16, lane), g1 = up0(sf1, 16, lane), g2 = up0(sf2, 16, lane);
  float h0 = dn0(sf0, 48, lane), h1 = dn0(sf1, 48, lane), h2 = dn0(sf2, 48, lane);
  wi[0] = g0 + M + L0;  wi[1] = g1 + M + L1;  wi[2] = g2 + M + L2;  wi[3] = M + L3;
  wt[0] = h0 + T49;     wt[1] = h1 + T49;     wt[2] = h2 + T49;     wt[3] = T49;
}

__device__ __forceinline__ float out_val(float ws, float ws2, float xc,
                                         float mean, float ssd) {
  const float FLOOR_  = 1.1920928955078125e-07f;  // float32 eps
  const float FLOOR2_ = FLOOR_ * FLOOR_;
  float num  = xc - ws * mean;
  float w2c  = ws2 - ws * ws * (1.0f / 4096.0f);
  float t    = fmaxf(w2c * ssd, 0.0f);            // denom^2
  float numc = fmaxf(num, FLOOR_);
  return (t > FLOOR2_) ? (numc * __frsqrt_rn(t)) : 0.0f;
}

__global__ __launch_bounds__(256, 4)
void ncc_norm_kernel(const float* __restrict__ feat1,
                     const float* __restrict__ feat2,
                     const float* __restrict__ xcorr,
                     float* __restrict__ out) {
  const int tid  = threadIdx.x;
  const int lane = tid & 63;
  const int wv   = tid >> 6;

  // XCD-chunked bijective swizzle for grid=1024 (= 8 XCD * 128):
  // a channel's 2 blocks (8 segments) are adjacent in dispatch order on one XCD.
  const int d   = blockIdx.x;          // 0..1023
  const int xcd = d & 7;
  const int i   = d >> 3;              // 0..127
  const int bc  = xcd * 64 + (i >> 1); // 0..511 channel
  const int seg = (i & 1) * 4 + wv;    // 0..7 row segment

  const float* f1 = feat1 + (size_t)bc * (H1 * W1);
  const float* f2 = feat2 + (size_t)bc * 4096;

  // ---- per-wave feat_2 stats ----
  float sum = 0.0f, sumsq = 0.0f;
  #pragma unroll
  for (int r = 0; r < 16; ++r) {
    float4 qq = *(const float4*)(f2 + r * 256 + 4 * lane);
    sum   += (qq.x + qq.y) + (qq.z + qq.w);
    sumsq += (qq.x * qq.x + qq.y * qq.y) + (qq.z * qq.z + qq.w * qq.w);
  }
  #pragma unroll
  for (int dd = 1; dd < 64; dd <<= 1) {
    sum   += __shfl_xor(sum,   dd, 64);
    sumsq += __shfl_xor(sumsq, dd, 64);
  }
  float mean = sum * (1.0f / 4096.0f);
  float ssd  = sumsq - sum * mean;

  const int y0 = seg * ROWS_PER;
  const int y1 = min(HO, y0 + ROWS_PER);
  const int x4 = 4 * lane;

  // ---- vertical running window sums (fp64; exact) ----
  double v0 = 0, v1 = 0, v2 = 0, v3 = 0;
  double q0 = 0, q1 = 0, q2 = 0, q3 = 0;
  for (int r = max(0, y0 - 64); r < min(y0, H1); ++r) {
    float4 t = *(const float4*)(f1 + r * W1 + x4);
    v0 += t.x; q0 += (double)t.x * t.x;
    v1 += t.y; q1 += (double)t.y * t.y;
    v2 += t.z; q2 += (double)t.z * t.z;
    v3 += t.w; q3 += (double)t.w * t.w;
  }

#define LOADF(row) (*(const float4*)(f1 + (row) * W1 + x4))

  // feat_1 pair-prefetch registers (entering A/B = rows y,y+1; leaving A/B)
  float4 eA, eB, lA, lB;
  {
    int yn = y0;
    if (yn < H1)                        eA = LOADF(yn);
    if (yn + 1 < H1 && yn + 1 < y1)     eB = LOADF(yn + 1);
    if (yn >= 64)                       lA = LOADF(yn - 64);
    if (yn + 1 >= 64 && yn + 1 < y1)    lB = LOADF(yn - 63);
  }

  int y = y0;
  for (; y + 1 < y1; y += 2) {
    const int rbA = (bc * HO + y) * WO;
    const int rbB = rbA + WO;
    const float* xrA = xcorr + rbA;
    const float* xrB = xcorr + rbB;

    // issue both rows' xcorr loads up front (consumed after 4x win7)
    float xiA[4], xiB[4];
    float xtA[4] = {0,0,0,0}, xtB[4] = {0,0,0,0};
    #pragma unroll
    for (int j = 0; j < 4; ++j) { xiA[j] = xrA[x4 + j]; xiB[j] = xrB[x4 + j]; }
    if (lane < 16) {
      xtA[0] = xrA[256 + x4 + 0]; xtB[0] = xrB[256 + x4 + 0];
      xtA[1] = xrA[256 + x4 + 1]; xtB[1] = xrB[256 + x4 + 1];
      xtA[2] = xrA[256 + x4 + 2]; xtB[2] = xrB[256 + x4 + 2];
      if (lane < 15) { xtA[3] = xrA[256 + x4 + 3]; xtB[3] = xrB[256 + x4 + 3]; }
    }

    // ---- row y: consume prefetched rows, snapshot ----
    if (y < H1) {
      v0 += eA.x; q0 += (double)eA.x * eA.x;
      v1 += eA.y; q1 += (double)eA.y * eA.y;
      v2 += eA.z; q2 += (double)eA.z * eA.z;
      v3 += eA.w; q3 += (double)eA.w * eA.w;
    }
    if (y >= 64) {
      v0 -= lA.x; q0 -= (double)lA.x * lA.x;
      v1 -= lA.y; q1 -= (double)lA.y * lA.y;
      v2 -= lA.z; q2 -= (double)lA.z * lA.z;
      v3 -= lA.w; q3 -= (double)lA.w * lA.w;
    }
    float wA0 = (float)v0, wA1 = (float)v1, wA2 = (float)v2, wA3 = (float)v3;
    float uA0 = (float)q0, uA1 = (float)q1, uA2 = (float)q2, uA3 = (float)q3;

    // ---- row y+1: consume, snapshot ----
    if (y + 1 < H1) {
      v0 += eB.x; q0 += (double)eB.x * eB.x;
      v1 += eB.y; q1 += (double)eB.y * eB.y;
      v2 += eB.z; q2 += (double)eB.z * eB.z;
      v3 += eB.w; q3 += (double)eB.w * eB.w;
    }
    if (y + 1 >= 64) {
      v0 -= lB.x; q0 -= (double)lB.x * lB.x;
      v1 -= lB.y; q1 -= (double)lB.y * lB.y;
      v2 -= lB.z; q2 -= (double)lB.z * lB.z;
      v3 -= lB.w; q3 -= (double)lB.w * lB.w;
    }
    float wB0 = (float)v0, wB1 = (float)v1, wB2 = (float)v2, wB3 = (float)v3;
    float uB0 = (float)q0, uB1 = (float)q1, uB2 = (float)q2, uB3 = (float)q3;

    // ---- prefetch feat_1 rows for next pair (hide L2/L3/HBM latency) ----
    {
      int yn = y + 2;
      if (yn < y1) {
        if (yn < H1)                     eA = LOADF(yn);
        if (yn + 1 < H1 && yn + 1 < y1)  eB = LOADF(yn + 1);
        if (yn >= 64)                    lA = LOADF(yn - 64);
        if (yn + 1 >= 64 && yn + 1 < y1) lB = LOADF(yn - 63);
      }
    }

    // ---- 4 independent shuffle chains (ILP across rows & quantities) ----
    float wsIA[4], wsTA[4], sqIA[4], sqTA[4];
    float wsIB[4], wsTB[4], sqIB[4], sqTB[4];
    win7(wA0, wA1, wA2, wA3, lane, wsIA, wsTA);
    win7(uA0, uA1, uA2, uA3, lane, sqIA, sqTA);
    win7(wB0, wB1, wB2, wB3, lane, wsIB, wsTB);
    win7(uB0, uB1, uB2, uB3, lane, sqIB, sqTB);

    float* oA = out + rbA;
    float* oB = out + rbB;
    #pragma unroll
    for (int j = 0; j < 4; ++j) {
      oA[x4 + j] = out_val(wsIA[j], sqIA[j], xiA[j], mean, ssd);
      oB[x4 + j] = out_val(wsIB[j], sqIB[j], xiB[j], mean, ssd);
    }
    if (lane < 16) {
      oA[256 + x4 + 0] = out_val(wsTA[0], sqTA[0], xtA[0], mean, ssd);
      oB[256 + x4 + 0] = out_val(wsTB[0], sqTB[0], xtB[0], mean, ssd);
      oA[256 + x4 + 1] = out_val(wsTA[1], sqTA[1], xtA[1], mean, ssd);
      oB[256 + x4 + 1] = out_val(wsTB[1], sqTB[1], xtB[1], mean, ssd);
      oA[256 + x4 + 2] = out_val(wsTA[2], sqTA[2], xtA[2], mean, ssd);
      oB[256 + x4 + 2] = out_val(wsTB[2], sqTB[2], xtB[2], mean, ssd);
      if (lane < 15) {
        oA[256 + x4 + 3] = out_val(wsTA[3], sqTA[3], xtA[3], mean, ssd);
        oB[256 + x4 + 3] = out_val(wsTB[3], sqTB[3], xtB[3], mean, ssd);
      }
    }
  }

  // ---- odd tail row (only last segment: 39 rows) ----
  if (y < y1) {
    const int rowbase = (bc * HO + y) * WO;
    const float* xr = xcorr + rowbase;
    float* orw      = out   + rowbase;

    float xi[4];
    float xt[4] = {0,0,0,0};
    #pragma unroll
    for (int j = 0; j < 4; ++j) xi[j] = xr[x4 + j];
    if (lane < 16) {
      xt[0] = xr[256 + x4 + 0];
      xt[1] = xr[256 + x4 + 1];
      xt[2] = xr[256 + x4 + 2];
      if (lane < 15) xt[3] = xr[256 + x4 + 3];
    }

    if (y < H1) {
      v0 += eA.x; q0 += (double)eA.x * eA.x;
      v1 += eA.y; q1 += (double)eA.y * eA.y;
      v2 += eA.z; q2 += (double)eA.z * eA.z;
      v3 += eA.w; q3 += (double)eA.w * eA.w;
    }
    if (y >= 64) {
      v0 -= lA.x; q0 -= (double)lA.x * lA.x;
      v1 -= lA.y; q1 -= (double)lA.y * lA.y;
      v2 -= lA.z; q2 -= (double)lA.z * lA.z;
      v3 -= lA.w; q3 -= (double)lA.w * lA.w;
    }
    float w0 = (float)v0, w1 = (float)v1, w2 = (float)v2, w3 = (float)v3;
    float u0 = (float)q0, u1 = (float)q1, u2 = (float)q2, u3 = (float)q3;

    float wsI[4], wsT[4], sqI[4], sqT[4];
    win7(w0, w1, w2, w3, lane, wsI, wsT);
    win7(u0, u1, u2, u3, lane, sqI, sqT);

    #pragma unroll
    for (int j = 0; j < 4; ++j)
      orw[x4 + j] = out_val(wsI[j], sqI[j], xi[j], mean, ssd);
    if (lane < 16) {
      orw[256 + x4 + 0] = out_val(wsT[0], sqT[0], xt[0], mean, ssd);
      orw[256 + x4 + 1] = out_val(wsT[1], sqT[1], xt[1], mean, ssd);
      orw[256 + x4 + 2] = out_val(wsT[2], sqT[2], xt[2], mean, ssd);
      if (lane < 15)
        orw[256 + x4 + 3] = out_val(wsT[3], sqT[3], xt[3], mean, ssd);
    }
  }
#undef LOADF
}

extern "C" void kernel_launch(void* const* d_in, const int* in_sizes, int n_in,
                              void* d_out, int out_size, void* d_ws, size_t ws_size,
                              hipStream_t stream) {
  const float* feat1 = (const float*)d_in[0];
  const float* feat2 = (const float*)d_in[1];
  const float* xcorr = (const float*)d_in[2];
  float* out = (float*)d_out;

  dim3 grid(512 * SEG / 4);   // 1024 blocks, 4 waves/block, one wave per (channel, segment)
  ncc_norm_kernel<<<grid, 256, 0, stream>>>(feat1, feat2, xcorr, out);
}